// Round 13
// baseline (562.735 us; speedup 1.0000x reference)
//
#include <hip/hip_runtime.h>

#define NBATCH 4
#define NPTS   4096
#define NP     (NBATCH*NPTS)   // 16384
#define KK     32
#define INF    __builtin_inff()

// ---------------- ws layout (float units) ----------------
static const size_t OFF_PTS  = 0;         // float4[NP]        65536
static const size_t OFF_IDX  = 65536;     // int[NP*32]       524288
static const size_t OFF_TSK  = 589824;    // float[NP*64]    1048576
static const size_t OFF_TC   = 1638400;   // float[NP*64]
static const size_t OFF_TGA  = 2686976;   // float[NP*64]
static const size_t OFF_PREL = 3735552;   // float[9] (pad 16)
static const size_t OFF_PSK  = 3735568;   // float[128]
static const size_t OFF_PTA  = 3735696;   // float[128]
static const size_t OFF_PTC  = 3735824;   // float[128]
static const size_t OFF_PTGA = 3735952;   // float[128]
static const size_t OFF_AFF  = 3736080;   // float[640]  -> ~15 MB total

typedef __bf16 bf16x8  __attribute__((ext_vector_type(8)));
typedef float  floatx16 __attribute__((ext_vector_type(16)));
#define MFMA32(a,b,c) __builtin_amdgcn_mfma_f32_32x32x16_bf16(a, b, c, 0, 0, 0)

union F8 { bf16x8 v; unsigned short us[8]; uint4 q4; };

__device__ __forceinline__ unsigned short bfbits(float f) {
  unsigned u = __float_as_uint(f);
  return (unsigned short)((u + 0x7FFFu + ((u >> 16) & 1u)) >> 16);
}
__device__ __forceinline__ floatx16 zero16() {
  floatx16 v;
#pragma unroll
  for (int i = 0; i < 16; ++i) v[i] = 0.f;
  return v;
}
__device__ __forceinline__ float wsum(float v) {
#pragma unroll
  for (int o = 32; o; o >>= 1) v += __shfl_xor(v, o, 64);
  return v;
}
__device__ __forceinline__ int isum(int v) {
#pragma unroll
  for (int o = 32; o; o >>= 1) v += __shfl_xor(v, o);
  return v;
}

// ---------------- 1: pts4 = (x,y,z,|p|^2) + zero all stat accumulators ----------------
__global__ __launch_bounds__(256,1) void k_prep(const float* __restrict__ x, float4* __restrict__ pts,
                                                float* __restrict__ pta, float* __restrict__ ptc,
                                                float* __restrict__ ptga, float* __restrict__ prel9,
                                                float* __restrict__ psk128) {
  if (blockIdx.x == 0) {
    if (threadIdx.x < 128) {
      pta[threadIdx.x] = 0.f; ptc[threadIdx.x] = 0.f; ptga[threadIdx.x] = 0.f;
      psk128[threadIdx.x] = 0.f;
    }
    if (threadIdx.x < 16) prel9[threadIdx.x] = 0.f;
  }
  int g = blockIdx.x * 256 + threadIdx.x;
  int b = g / NPTS, n = g % NPTS;
  float vx = x[(b*3+0)*NPTS + n];
  float vy = x[(b*3+1)*NPTS + n];
  float vz = x[(b*3+2)*NPTS + n];
  pts[g] = make_float4(vx, vy, vz, vx*vx + vy*vy + vz*vz);
}

// ---------------- 2: kNN: LDS tile + (key,idx) pair top-5 in registers -> bisect ----------------
// -> register collect (no keys[] array, no scratch spill). Rare exact fallback (P~1%)
// recomputes distances from global (L2-warm, bit-identical fmaf chain). Fused stats epilogue.
__global__ __launch_bounds__(256) void k_knn(const float4* __restrict__ pts, int* __restrict__ idx,
                                             const float* __restrict__ Wsk, float* __restrict__ tsk,
                                             float* __restrict__ prel9, float* __restrict__ psk128) {
  __shared__ __align__(16) float4 tile[1024];   // 16 KB staging
  __shared__ int ocnt[4];
  __shared__ int lsel[128];                      // selected indices, per wave
  __shared__ float rsum[9], psum[64], pss[64];
  const int tid  = threadIdx.x;
  const int w    = tid >> 6;
  const int lane = tid & 63;
  if (tid < 9)  rsum[tid] = 0.f;
  if (tid < 64) { psum[tid] = 0.f; pss[tid] = 0.f; }
  __syncthreads();
  const int n = blockIdx.x * 4 + w;
  const int batch = n >> 12;
  const float4* base = pts + batch * NPTS;
  const float4 me = pts[n];
  const float wk0 = Wsk[lane*6+0], wk1 = Wsk[lane*6+1], wk2 = Wsk[lane*6+2],
              wk3 = Wsk[lane*6+3], wk4 = Wsk[lane*6+4], wk5 = Wsk[lane*6+5];

  // ---- pass 1: tile staging + distances + sorted (key,idx) top-5 per lane ----
  unsigned ka0 = 0xFFFFFFFFu, ka1 = 0xFFFFFFFFu, ka2 = 0xFFFFFFFFu,
           ka3 = 0xFFFFFFFFu, ka4 = 0xFFFFFFFFu;
  int ia0 = 0, ia1 = 0, ia2 = 0, ia3 = 0, ia4 = 0;
#define PINS(KR, IR) { bool cc = key < KR; unsigned tk = cc ? KR : key; int ti = cc ? IR : id; \
                       KR = cc ? key : KR; IR = cc ? id : IR; key = tk; id = ti; }
  for (int st = 0; st < 4; ++st) {
    __syncthreads();
#pragma unroll
    for (int r = 0; r < 4; ++r)
      tile[r*256 + tid] = base[st*1024 + r*256 + tid];
    __syncthreads();
#pragma unroll
    for (int j = 0; j < 16; ++j) {
      float4 p = tile[j*64 + lane];
      float dot = fmaf(me.x, p.x, fmaf(me.y, p.y, me.z * p.z));
      float d = fmaxf(fmaf(-2.f, dot, me.w + p.w), 0.f);
      unsigned key = __float_as_uint(d);        // positive floats order as uints
      int id = st*1024 + j*64 + lane;
      PINS(ka0, ia0) PINS(ka1, ia1) PINS(ka2, ia2) PINS(ka3, ia3) PINS(ka4, ia4)
    }
  }
#undef PINS

  // ---- wave bounds: tau in [min(ka0), max(ka4)] ----
  unsigned glo = ka0, ghi = ka4;
#pragma unroll
  for (int o = 32; o; o >>= 1) {
    glo = min(glo, (unsigned)__shfl_xor((int)glo, o));
    ghi = max(ghi, (unsigned)__shfl_xor((int)ghi, o));
  }

  // ---- bisect over per-lane top-5 ----
  unsigned lo = glo, hi = ghi, tau = ghi;
  bool exact = false;
  while (lo < hi) {
    unsigned mid = lo + ((hi - lo) >> 1);
    int c = (ka0 <= mid) + (ka1 <= mid) + (ka2 <= mid) + (ka3 <= mid) + (ka4 <= mid);
    c = isum(c);
    if (c == 32) { tau = mid; exact = true; break; }
    if (c > 32) hi = mid; else lo = mid + 1;
  }
  if (!exact) tau = lo;

  if (lane == 0) ocnt[w] = 0;
  int* op = idx + n * KK;

  if (__ballot(ka4 <= tau) == 0ull) {
    // ---- normal path: collect straight from the 5 register pairs ----
    unsigned kk[5] = { ka0, ka1, ka2, ka3, ka4 };
    int      ii[5] = { ia0, ia1, ia2, ia3, ia4 };
#pragma unroll
    for (int r = 0; r < 5; ++r) {
      bool take = exact ? (kk[r] <= tau) : (kk[r] < tau);
      if (take) {
        int s = atomicAdd(&ocnt[w], 1);
        op[s] = ii[r]; lsel[w*32 + s] = ii[r];
      }
    }
    if (!exact) {
      unsigned used = 0;
      int n1 = ocnt[w];
      int need = KK - n1;
      for (int f = 0; f < need; ++f) {
        int my = 0x7FFFFFFF, which = -1;
#pragma unroll
        for (int r = 0; r < 5; ++r)
          if (!((used >> r) & 1) && kk[r] == tau && ii[r] < my) { my = ii[r]; which = r; }
        int g = my;
#pragma unroll
        for (int o = 32; o; o >>= 1) g = min(g, __shfl_xor(g, o));
        if (my == g && which >= 0) { used |= 1u << which; op[n1 + f] = my; lsel[w*32 + n1 + f] = my; }
      }
    }
  } else {
    // ---- rare exact fallback (~1% of waves): recompute-based bisect + collect over [glo, tau] ----
    lo = glo; hi = tau; exact = false;
    while (lo < hi) {
      unsigned mid = lo + ((hi - lo) >> 1);
      int c = 0;
      for (int j = 0; j < 64; ++j) {
        float4 p = base[j*64 + lane];
        float dot = fmaf(me.x, p.x, fmaf(me.y, p.y, me.z * p.z));
        float d = fmaxf(fmaf(-2.f, dot, me.w + p.w), 0.f);
        c += (__float_as_uint(d) <= mid) ? 1 : 0;
      }
      c = isum(c);
      if (c == 32) { tau = mid; exact = true; break; }
      if (c > 32) hi = mid; else lo = mid + 1;
    }
    if (!exact) tau = lo;
    unsigned long long em = 0;
    for (int j = 0; j < 64; ++j) {
      float4 p = base[j*64 + lane];
      float dot = fmaf(me.x, p.x, fmaf(me.y, p.y, me.z * p.z));
      float d = fmaxf(fmaf(-2.f, dot, me.w + p.w), 0.f);
      unsigned key = __float_as_uint(d);
      bool take = exact ? (key <= tau) : (key < tau);
      if (take) {
        int s = atomicAdd(&ocnt[w], 1);
        int m = j*64 + lane;
        if (s < KK) { op[s] = m; lsel[w*32 + s] = m; }
      }
      if (key == tau) em |= 1ull << j;
    }
    if (!exact) {
      int n1 = ocnt[w];
      int need = KK - n1;
      for (int f = 0; f < need; ++f) {
        int myj = em ? (int)__builtin_ctzll(em) : 64;
        int mym = (myj < 64) ? (myj*64 + lane) : 0x7FFFFFFF;
        int g = mym;
#pragma unroll
        for (int o = 32; o; o >>= 1) g = min(g, __shfl_xor(g, o));
        if (mym == g && myj < 64) { em &= em - 1; op[n1 + f] = mym; lsel[w*32 + n1 + f] = mym; }
      }
    }
  }

  // ---- fused stats epilogue ----
  int mi = lsel[w*32 + (lane & 31)];
  float4 p = base[mi];
  bool act = lane < 32;
  float r0 = act ? p.x - me.x : 0.f;
  float r1 = act ? p.y - me.y : 0.f;
  float r2 = act ? p.z - me.z : 0.f;
  float vals[9] = { r0, r1, r2, r0*r0, r0*r1, r0*r2, r1*r1, r1*r2, r2*r2 };
#pragma unroll
  for (int t = 0; t < 9; ++t) {
    float rs = wsum(vals[t]);
    if (lane == 0) atomicAdd(&rsum[t], rs);
  }
  float nx = act ? p.x : -INF, ny = act ? p.y : -INF, nz = act ? p.z : -INF;
#pragma unroll
  for (int o = 32; o; o >>= 1) {
    nx = fmaxf(nx, __shfl_xor(nx, o));
    ny = fmaxf(ny, __shfl_xor(ny, o));
    nz = fmaxf(nz, __shfl_xor(nz, o));
  }
  float ts = fmaf(me.x, wk0, fmaf(me.y, wk1, fmaf(me.z, wk2,
             fmaf(nx, wk3, fmaf(ny, wk4, nz * wk5)))));
  tsk[n*64 + lane] = ts;
  atomicAdd(&psum[lane], ts);
  atomicAdd(&pss[lane], ts * ts);
  __syncthreads();
  if (tid < 9)  atomicAdd(&prel9[tid], rsum[tid]);
  if (tid < 64) atomicAdd(&psk128[tid], psum[tid]);
  else if (tid < 128) atomicAdd(&psk128[tid], pss[tid - 64]);
}

// ---------------- 3: finalize BN1 (from rel moments) and BN_sk ----------------
__global__ __launch_bounds__(64,1) void k_fin1(const float* __restrict__ prel9, const float* __restrict__ psk128,
                                               const float* __restrict__ Wp1,
                                               const float* __restrict__ g_p, const float* __restrict__ b_p,
                                               const float* __restrict__ g_sk, const float* __restrict__ b_sk,
                                               float* __restrict__ aff) {
  int d = threadIdx.x;
  double C = (double)NP * (double)KK;
  double mr0 = prel9[0]/C, mr1 = prel9[1]/C, mr2 = prel9[2]/C;
  double e00 = prel9[3]/C, e01 = prel9[4]/C, e02 = prel9[5]/C;
  double e11 = prel9[6]/C, e12 = prel9[7]/C, e22 = prel9[8]/C;
  double w0 = Wp1[d*3+0], w1 = Wp1[d*3+1], w2 = Wp1[d*3+2];
  double mu  = w0*mr0 + w1*mr1 + w2*mr2;
  double ex2 = w0*w0*e00 + w1*w1*e11 + w2*w2*e22 + 2.0*(w0*w1*e01 + w0*w2*e02 + w1*w2*e12);
  double var = ex2 - mu*mu;
  double sc  = (double)g_p[d] / sqrt(var + 1e-5);
  aff[0*64 + d] = (float)sc;
  aff[1*64 + d] = (float)((double)b_p[d] - mu*sc);
  double mean = (double)psk128[d] / (double)NP;
  double v2   = (double)psk128[64+d] / (double)NP - mean*mean;
  double sc4  = (double)g_sk[d] / sqrt(v2 + 1e-5);
  aff[6*64 + d] = (float)sc4;
  aff[7*64 + d] = (float)((double)b_sk[d] - mean*sc4);
}

// ---------------- tiny finalize from 128-word global accumulator ----------------
__global__ __launch_bounds__(64,1) void k_fin2(const float* __restrict__ st, double C,
                                               const float* __restrict__ g, const float* __restrict__ b,
                                               float* __restrict__ s_out, float* __restrict__ o_out) {
  int d = threadIdx.x;
  double mean = (double)st[d] / C;
  double var  = (double)st[64 + d] / C - mean*mean;
  double sc   = (double)g[d] / sqrt(var + 1e-5);
  s_out[d] = (float)sc;
  o_out[d] = (float)((double)b[d] - mean*sc);
}

// ---------------- MFMA entry chain: MODE 0 = t_a stats; MODE 1 = softmax/agg/t_c ----------------
// round-12 proven config: 8 points/wave, 512 blocks, next-point gather prefetch.
template<int MODE>
__global__ __launch_bounds__(256,1) void k_entry(const float4* __restrict__ pts, const int* __restrict__ idx,
                                                 const float* __restrict__ Wq, const float* __restrict__ Wkv,
                                                 const float* __restrict__ Wp1, const float* __restrict__ Wp2,
                                                 const float* __restrict__ Wa, const float* __restrict__ Wc1,
                                                 const float* __restrict__ aff, float* __restrict__ pstats,
                                                 float* __restrict__ tc) {
  __shared__ __align__(16) unsigned short ybuf[4][32][72];
  __shared__ __align__(16) float aggbuf[4][64];
  __shared__ float psum[64], pss[64];
  if (threadIdx.x < 64) { psum[threadIdx.x] = 0.f; pss[threadIdx.x] = 0.f; }
  __syncthreads();
  const int lane = threadIdx.x & 63;
  const int w    = threadIdx.x >> 6;
  const int c    = lane & 31;
  const int q5   = lane >> 5;

  F8 B0[2];
#pragma unroll
  for (int nt = 0; nt < 2; ++nt)
#pragma unroll
    for (int t = 0; t < 8; ++t)
      B0[nt].us[t] = (q5 == 0 && t < 3) ? bfbits(Wp1[(nt*32+c)*3 + t]) : (unsigned short)0;

  F8 Bs[4][2], B2[4][2];
#pragma unroll
  for (int kt = 0; kt < 4; ++kt)
#pragma unroll
    for (int h = 0; h < 2; ++h) {
      const float* p2 = Wp2 + (h*32+c)*64 + kt*16 + q5*8;
      float4 a = *(const float4*)p2, b = *(const float4*)(p2 + 4);
      Bs[kt][h].us[0]=bfbits(a.x); Bs[kt][h].us[1]=bfbits(a.y); Bs[kt][h].us[2]=bfbits(a.z); Bs[kt][h].us[3]=bfbits(a.w);
      Bs[kt][h].us[4]=bfbits(b.x); Bs[kt][h].us[5]=bfbits(b.y); Bs[kt][h].us[6]=bfbits(b.z); Bs[kt][h].us[7]=bfbits(b.w);
      const float* pa = Wa + (h*32+c)*64 + kt*16 + q5*8;
      float4 e = *(const float4*)pa, f = *(const float4*)(pa + 4);
      B2[kt][h].us[0]=bfbits(e.x); B2[kt][h].us[1]=bfbits(e.y); B2[kt][h].us[2]=bfbits(e.z); B2[kt][h].us[3]=bfbits(e.w);
      B2[kt][h].us[4]=bfbits(f.x); B2[kt][h].us[5]=bfbits(f.y); B2[kt][h].us[6]=bfbits(f.z); B2[kt][h].us[7]=bfbits(f.w);
    }

  F8 Bk4[4];
#pragma unroll
  for (int nt = 0; nt < 4; ++nt) {
    if (MODE == 0 && nt >= 2) { for (int t = 0; t < 8; ++t) Bk4[nt].us[t] = 0; continue; }
    int e = (nt & 1)*32 + c;
#pragma unroll
    for (int t = 0; t < 8; ++t)
      Bk4[nt].us[t] = (q5 == 0 && t < 3)
        ? bfbits(nt < 2 ? -Wkv[e*3 + t] : Wkv[(64+e)*3 + t]) : (unsigned short)0;
  }

  const float s1a = aff[c],      o1a = aff[64+c];
  const float s1b = aff[32+c],   o1b = aff[96+c];
  float s2a = 0.f, o2a = 0.f, s2b = 0.f, o2b = 0.f;
  if (MODE == 1) { s2a = aff[128+c]; o2a = aff[192+c]; s2b = aff[160+c]; o2b = aff[224+c]; }
  const float wqa0 = Wq[c*3+0],      wqa1 = Wq[c*3+1],      wqa2 = Wq[c*3+2];
  const float wqb0 = Wq[(32+c)*3+0], wqb1 = Wq[(32+c)*3+1], wqb2 = Wq[(32+c)*3+2];

  const int wave_id = blockIdx.x * 4 + w;
  const int n0 = wave_id * 8;
  const int batch = n0 >> 12;
  const float4* base = pts + batch * NPTS;

  // prefetch point 0's gather
  float4 me = pts[n0];
  float4 pp = base[idx[n0*KK + c]];

  for (int pi = 0; pi < 8; ++pi) {
    const int n = n0 + pi;
    // issue next point's gather before this point's compute chain
    float4 men = me, ppn = pp;
    if (pi < 7) {
      men = pts[n + 1];
      ppn = base[idx[(n + 1)*KK + c]];
    }
    const float r0 = pp.x - me.x, r1 = pp.y - me.y, r2 = pp.z - me.z;
    F8 relA;
#pragma unroll
    for (int t = 0; t < 8; ++t) relA.us[t] = 0;
    if (q5 == 0) { relA.us[0] = bfbits(r0); relA.us[1] = bfbits(r1); relA.us[2] = bfbits(r2); }

    const floatx16 z = zero16();
    floatx16 y0 = MFMA32(relA.v, B0[0].v, z);
    floatx16 y1 = MFMA32(relA.v, B0[1].v, z);
#pragma unroll
    for (int r = 0; r < 16; ++r) {
      int row = (r & 3) + 8*(r >> 2) + 4*q5;
      ybuf[w][row][c]      = bfbits(fmaxf(fmaf(y0[r], s1a, o1a), 0.f));
      ybuf[w][row][32 + c] = bfbits(fmaxf(fmaf(y1[r], s1b, o1b), 0.f));
    }
    F8 Ay[4];
#pragma unroll
    for (int kt = 0; kt < 4; ++kt) Ay[kt].q4 = *(const uint4*)&ybuf[w][c][kt*16 + q5*8];

    floatx16 Cp0 = z, Cp1 = z;
#pragma unroll
    for (int kt = 0; kt < 4; ++kt) {
      Cp0 = MFMA32(Ay[kt].v, Bs[kt][0].v, Cp0);
      Cp1 = MFMA32(Ay[kt].v, Bs[kt][1].v, Cp1);
    }
    floatx16 Cu0 = MFMA32(relA.v, Bk4[0].v, Cp0);
    floatx16 Cu1 = MFMA32(relA.v, Bk4[1].v, Cp1);
    if (MODE == 1) {
      Cp0 = MFMA32(relA.v, Bk4[2].v, Cp0);
      Cp1 = MFMA32(relA.v, Bk4[3].v, Cp1);
    }
    const float qa = fmaf(me.x, wqa0, fmaf(me.y, wqa1, me.z * wqa2));
    const float qb = fmaf(me.x, wqb0, fmaf(me.y, wqb1, me.z * wqb2));
#pragma unroll
    for (int r = 0; r < 16; ++r) {
      int row = (r & 3) + 8*(r >> 2) + 4*q5;
      ybuf[w][row][c]      = bfbits(Cu0[r] + qa);
      ybuf[w][row][32 + c] = bfbits(Cu1[r] + qb);
    }
    F8 Au[4];
#pragma unroll
    for (int kt = 0; kt < 4; ++kt) Au[kt].q4 = *(const uint4*)&ybuf[w][c][kt*16 + q5*8];
    floatx16 Ct0 = z, Ct1 = z;
#pragma unroll
    for (int kt = 0; kt < 4; ++kt) {
      Ct0 = MFMA32(Au[kt].v, B2[kt][0].v, Ct0);
      Ct1 = MFMA32(Au[kt].v, B2[kt][1].v, Ct1);
    }

    if (MODE == 0) {
      float sa = 0.f, qqa = 0.f, sb = 0.f, qqb = 0.f;
#pragma unroll
      for (int r = 0; r < 16; ++r) {
        sa += Ct0[r]; qqa = fmaf(Ct0[r], Ct0[r], qqa);
        sb += Ct1[r]; qqb = fmaf(Ct1[r], Ct1[r], qqb);
      }
      sa += __shfl_xor(sa, 32); qqa += __shfl_xor(qqa, 32);
      sb += __shfl_xor(sb, 32); qqb += __shfl_xor(qqb, 32);
      if (q5 == 0) {
        atomicAdd(&psum[c], sa);      atomicAdd(&pss[c], qqa);
        atomicAdd(&psum[32+c], sb);   atomicAdd(&pss[32+c], qqb);
      }
    } else {
      float ma = -INF, mb = -INF;
#pragma unroll
      for (int r = 0; r < 16; ++r) {
        float la = fmaxf(fmaf(Ct0[r], s2a, o2a), 0.f); Ct0[r] = la; ma = fmaxf(ma, la);
        float lb = fmaxf(fmaf(Ct1[r], s2b, o2b), 0.f); Ct1[r] = lb; mb = fmaxf(mb, lb);
      }
      ma = fmaxf(ma, __shfl_xor(ma, 32));
      mb = fmaxf(mb, __shfl_xor(mb, 32));
      float sa = 0.f, sb = 0.f, aga = 0.f, agb = 0.f;
#pragma unroll
      for (int r = 0; r < 16; ++r) {
        float ta = __expf(Ct0[r] - ma); sa += ta; aga = fmaf(ta, Cp0[r], aga);
        float tb = __expf(Ct1[r] - mb); sb += tb; agb = fmaf(tb, Cp1[r], agb);
      }
      sa += __shfl_xor(sa, 32); aga += __shfl_xor(aga, 32);
      sb += __shfl_xor(sb, 32); agb += __shfl_xor(agb, 32);
      if (q5 == 0) {
        aggbuf[w][c]      = aga / sa;
        aggbuf[w][32 + c] = agb / sb;
      }
      float acc = 0.f;
#pragma unroll
      for (int g = 0; g < 16; ++g) {
        float4 av = *(const float4*)&aggbuf[w][g*4];
        const float4 wv = *(const float4*)(Wc1 + lane*64 + g*4);
        acc = fmaf(av.x, wv.x, fmaf(av.y, wv.y, fmaf(av.z, wv.z, fmaf(av.w, wv.w, acc))));
      }
      tc[n*64 + lane] = acc;
      atomicAdd(&psum[lane], acc);
      atomicAdd(&pss[lane], acc * acc);
    }
    me = men; pp = ppn;
  }
  __syncthreads();
  if (threadIdx.x < 64) atomicAdd(&pstats[threadIdx.x], psum[threadIdx.x]);
  else if (threadIdx.x < 128) atomicAdd(&pstats[threadIdx.x], pss[threadIdx.x - 64]);
}

// ---------------- t_ga = concat(h, sk) @ Wga^T + its stats ----------------
__global__ __launch_bounds__(256,1) void k_final(const float* __restrict__ tcb, const float* __restrict__ tskb,
                                                 const float* __restrict__ Wga, const float* __restrict__ aff,
                                                 float* __restrict__ tga, float* __restrict__ pstats) {
  __shared__ __align__(16) float hb[4][64];
  __shared__ __align__(16) float sb[4][64];
  __shared__ float psum[64], pss[64];
  if (threadIdx.x < 64) { psum[threadIdx.x] = 0.f; pss[threadIdx.x] = 0.f; }
  __syncthreads();
  const int lane = threadIdx.x & 63;
  const int w    = threadIdx.x >> 6;
  const int n = blockIdx.x * 4 + w;
  hb[w][lane] = fmaxf(fmaf(tcb[n*64 + lane],  aff[256 + lane], aff[320 + lane]), 0.f);
  sb[w][lane] = fmaxf(fmaf(tskb[n*64 + lane], aff[384 + lane], aff[448 + lane]), 0.f);
  float g0=0,g1=0,g2=0,g3=0;
#pragma unroll
  for (int d = 0; d < 64; d += 4) {
    const float4 hv = *(const float4*)&hb[w][d];
    const float4 wg = *(const float4*)(Wga + lane*128 + d);
    g0 = fmaf(hv.x, wg.x, g0);
    g1 = fmaf(hv.y, wg.y, g1);
    g2 = fmaf(hv.z, wg.z, g2);
    g3 = fmaf(hv.w, wg.w, g3);
  }
#pragma unroll
  for (int d = 0; d < 64; d += 4) {
    const float4 sv = *(const float4*)&sb[w][d];
    const float4 wg = *(const float4*)(Wga + lane*128 + 64 + d);
    g0 = fmaf(sv.x, wg.x, g0);
    g1 = fmaf(sv.y, wg.y, g1);
    g2 = fmaf(sv.z, wg.z, g2);
    g3 = fmaf(sv.w, wg.w, g3);
  }
  const float tg = (g0+g1) + (g2+g3);
  tga[n*64 + lane] = tg;
  atomicAdd(&psum[lane], tg);
  atomicAdd(&pss[lane], tg * tg);
  __syncthreads();
  if (threadIdx.x < 64) atomicAdd(&pstats[threadIdx.x], psum[threadIdx.x]);
  else if (threadIdx.x < 128) atomicAdd(&pstats[threadIdx.x], pss[threadIdx.x - 64]);
}

// ---------------- output: relu(BN5) + transpose to (B,64,N) ----------------
__global__ __launch_bounds__(256,1) void k_out(const float* __restrict__ tga, const float* __restrict__ aff,
                                               float* __restrict__ out) {
  int g = blockIdx.x * 256 + threadIdx.x;
  int nn = g & 4095;
  int e  = (g >> 12) & 63;
  int b  = g >> 18;
  float v = tga[((b << 12) + nn) * 64 + e];
  out[g] = fmaxf(fmaf(v, aff[512 + e], aff[576 + e]), 0.f);
}

extern "C" void kernel_launch(void* const* d_in, const int* in_sizes, int n_in,
                              void* d_out, int out_size, void* d_ws, size_t ws_size,
                              hipStream_t stream) {
  const float* x    = (const float*)d_in[0];
  const float* Wq   = (const float*)d_in[1];
  const float* Wkv  = (const float*)d_in[2];
  const float* Wp1  = (const float*)d_in[3];
  const float* Wp2  = (const float*)d_in[4];
  const float* Wa   = (const float*)d_in[5];
  const float* Wc1  = (const float*)d_in[6];
  const float* Wsk  = (const float*)d_in[7];
  const float* Wga  = (const float*)d_in[8];
  const float* g_p  = (const float*)d_in[9];
  const float* b_p  = (const float*)d_in[10];
  const float* g_a  = (const float*)d_in[11];
  const float* b_a  = (const float*)d_in[12];
  const float* g_c  = (const float*)d_in[13];
  const float* b_c  = (const float*)d_in[14];
  const float* g_sk = (const float*)d_in[15];
  const float* b_sk = (const float*)d_in[16];
  const float* g_ga = (const float*)d_in[17];
  const float* b_ga = (const float*)d_in[18];
  float* W = (float*)d_ws;
  float4*  pts   = (float4*)(W + OFF_PTS);
  int*     idx   = (int*)(W + OFF_IDX);
  float*   tsk   = W + OFF_TSK;
  float*   tc    = W + OFF_TC;
  float*   tga   = W + OFF_TGA;
  float*   prel9 = W + OFF_PREL;
  float*   psk   = W + OFF_PSK;
  float*   pta   = W + OFF_PTA;
  float*   ptc   = W + OFF_PTC;
  float*   ptga  = W + OFF_PTGA;
  float*   aff   = W + OFF_AFF;
  float*   out   = (float*)d_out;

  k_prep<<<64, 256, 0, stream>>>(x, pts, pta, ptc, ptga, prel9, psk);
  k_knn<<<4096, 256, 0, stream>>>(pts, idx, Wsk, tsk, prel9, psk);
  k_fin1<<<1, 64, 0, stream>>>(prel9, psk, Wp1, g_p, b_p, g_sk, b_sk, aff);
  k_entry<0><<<512, 256, 0, stream>>>(pts, idx, Wq, Wkv, Wp1, Wp2, Wa, nullptr, aff, pta, nullptr);
  k_fin2<<<1, 64, 0, stream>>>(pta, (double)NP * (double)KK, g_a, b_a, aff + 128, aff + 192);
  k_entry<1><<<512, 256, 0, stream>>>(pts, idx, Wq, Wkv, Wp1, Wp2, Wa, Wc1, aff, ptc, tc);
  k_fin2<<<1, 64, 0, stream>>>(ptc, (double)NP, g_c, b_c, aff + 256, aff + 320);
  k_final<<<4096, 256, 0, stream>>>(tc, tsk, Wga, aff, tga, ptga);
  k_fin2<<<1, 64, 0, stream>>>(ptga, (double)NP, g_ga, b_ga, aff + 512, aff + 576);
  k_out<<<4096, 256, 0, stream>>>(tga, aff, out);
}

// Round 14
// 546.624 us; speedup vs baseline: 1.0295x; 1.0295x over previous
//
#include <hip/hip_runtime.h>

#define NBATCH 4
#define NPTS   4096
#define NP     (NBATCH*NPTS)   // 16384
#define KK     32
#define INF    __builtin_inff()

// ---------------- ws layout (float units) ----------------
static const size_t OFF_PTS  = 0;         // float4[NP]        65536
static const size_t OFF_IDX  = 65536;     // int[NP*32]       524288
static const size_t OFF_TSK  = 589824;    // float[NP*64]    1048576
static const size_t OFF_TC   = 1638400;   // float[NP*64]
static const size_t OFF_TGA  = 2686976;   // float[NP*64]
static const size_t OFF_PREL = 3735552;   // float[9] (pad 16)
static const size_t OFF_PSK  = 3735568;   // float[128]
static const size_t OFF_PTA  = 3735696;   // float[128]
static const size_t OFF_PTC  = 3735824;   // float[128]
static const size_t OFF_PTGA = 3735952;   // float[128]
static const size_t OFF_AFF  = 3736080;   // float[640]  -> ~15 MB total

typedef __bf16 bf16x8  __attribute__((ext_vector_type(8)));
typedef float  floatx16 __attribute__((ext_vector_type(16)));
#define MFMA32(a,b,c) __builtin_amdgcn_mfma_f32_32x32x16_bf16(a, b, c, 0, 0, 0)

union F8 { bf16x8 v; unsigned short us[8]; uint4 q4; };

__device__ __forceinline__ unsigned short bfbits(float f) {
  unsigned u = __float_as_uint(f);
  return (unsigned short)((u + 0x7FFFu + ((u >> 16) & 1u)) >> 16);
}
__device__ __forceinline__ floatx16 zero16() {
  floatx16 v;
#pragma unroll
  for (int i = 0; i < 16; ++i) v[i] = 0.f;
  return v;
}
__device__ __forceinline__ float wsum(float v) {
#pragma unroll
  for (int o = 32; o; o >>= 1) v += __shfl_xor(v, o, 64);
  return v;
}
__device__ __forceinline__ int isum(int v) {
#pragma unroll
  for (int o = 32; o; o >>= 1) v += __shfl_xor(v, o);
  return v;
}

// ---------------- 1: pts4 = (x,y,z,|p|^2) + zero all stat accumulators ----------------
__global__ __launch_bounds__(256,1) void k_prep(const float* __restrict__ x, float4* __restrict__ pts,
                                                float* __restrict__ pta, float* __restrict__ ptc,
                                                float* __restrict__ ptga, float* __restrict__ prel9,
                                                float* __restrict__ psk128) {
  if (blockIdx.x == 0) {
    if (threadIdx.x < 128) {
      pta[threadIdx.x] = 0.f; ptc[threadIdx.x] = 0.f; ptga[threadIdx.x] = 0.f;
      psk128[threadIdx.x] = 0.f;
    }
    if (threadIdx.x < 16) prel9[threadIdx.x] = 0.f;
  }
  int g = blockIdx.x * 256 + threadIdx.x;
  int b = g / NPTS, n = g % NPTS;
  float vx = x[(b*3+0)*NPTS + n];
  float vy = x[(b*3+1)*NPTS + n];
  float vz = x[(b*3+2)*NPTS + n];
  pts[g] = make_float4(vx, vy, vz, vx*vx + vy*vy + vz*vz);
}

// ---------------- 2: kNN: key-only top-5 (short chain) -> bisect -> LDS-restage collect ----------------
// No keys[64] (round-12 scratch) and no pair network (round-13 chain). Collect re-stages the
// LDS tiles (L2-hot) and recomputes distances with a bit-identical fmaf chain. Fused stats.
__global__ __launch_bounds__(256) void k_knn(const float4* __restrict__ pts, int* __restrict__ idx,
                                             const float* __restrict__ Wsk, float* __restrict__ tsk,
                                             float* __restrict__ prel9, float* __restrict__ psk128) {
  __shared__ __align__(16) float4 tile[1024];   // 16 KB staging
  __shared__ int ocnt[4];
  __shared__ int lsel[128];                      // selected indices, per wave
  __shared__ float rsum[9], psum[64], pss[64];
  const int tid  = threadIdx.x;
  const int w    = tid >> 6;
  const int lane = tid & 63;
  if (tid < 9)  rsum[tid] = 0.f;
  if (tid < 64) { psum[tid] = 0.f; pss[tid] = 0.f; }
  __syncthreads();
  const int n = blockIdx.x * 4 + w;
  const int batch = n >> 12;
  const float4* base = pts + batch * NPTS;
  const float4 me = pts[n];
  const float wk0 = Wsk[lane*6+0], wk1 = Wsk[lane*6+1], wk2 = Wsk[lane*6+2],
              wk3 = Wsk[lane*6+3], wk4 = Wsk[lane*6+4], wk5 = Wsk[lane*6+5];

  // ---- pass 1: stage tiles + distances + key-only sorted top-5 per lane ----
  unsigned t0 = 0xFFFFFFFFu, t1 = 0xFFFFFFFFu, t2 = 0xFFFFFFFFu,
           t3 = 0xFFFFFFFFu, t4 = 0xFFFFFFFFu;
  for (int st = 0; st < 4; ++st) {
    __syncthreads();
#pragma unroll
    for (int r = 0; r < 4; ++r)
      tile[r*256 + tid] = base[st*1024 + r*256 + tid];
    __syncthreads();
#pragma unroll
    for (int j = 0; j < 16; ++j) {
      float4 p = tile[j*64 + lane];
      float dot = fmaf(me.x, p.x, fmaf(me.y, p.y, me.z * p.z));
      float d = fmaxf(fmaf(-2.f, dot, me.w + p.w), 0.f);
      unsigned m = __float_as_uint(d), x;       // positive floats order as uints
      x = min(t0, m); m = max(t0, m); t0 = x;
      x = min(t1, m); m = max(t1, m); t1 = x;
      x = min(t2, m); m = max(t2, m); t2 = x;
      x = min(t3, m); m = max(t3, m); t3 = x;
      t4 = min(t4, m);
    }
  }

  // ---- wave bounds ----
  unsigned glo = t0, ghi = t4;
#pragma unroll
  for (int o = 32; o; o >>= 1) {
    glo = min(glo, (unsigned)__shfl_xor((int)glo, o));
    ghi = max(ghi, (unsigned)__shfl_xor((int)ghi, o));
  }

  // ---- bisect over per-lane top-5 ----
  unsigned lo = glo, hi = ghi, tau = ghi;
  bool exact = false;
  while (lo < hi) {
    unsigned mid = lo + ((hi - lo) >> 1);
    int c = (t0 <= mid) + (t1 <= mid) + (t2 <= mid) + (t3 <= mid) + (t4 <= mid);
    c = isum(c);
    if (c == 32) { tau = mid; exact = true; break; }
    if (c > 32) hi = mid; else lo = mid + 1;
  }
  if (!exact) tau = lo;

  // ---- validity: any lane with t4 <= tau may be under-counted -> exact global fallback (~1e-3) ----
  if (__ballot(t4 <= tau) != 0ull) {
    lo = glo; hi = ghi; tau = ghi; exact = false;
    while (lo < hi) {
      unsigned mid = lo + ((hi - lo) >> 1);
      int c = 0;
      for (int j = 0; j < 64; ++j) {
        float4 p = base[j*64 + lane];
        float dot = fmaf(me.x, p.x, fmaf(me.y, p.y, me.z * p.z));
        float d = fmaxf(fmaf(-2.f, dot, me.w + p.w), 0.f);
        c += (__float_as_uint(d) <= mid) ? 1 : 0;
      }
      c = isum(c);
      if (c == 32) { tau = mid; exact = true; break; }
      if (c > 32) hi = mid; else lo = mid + 1;
    }
    if (!exact) tau = lo;
  }

  // ---- collect: re-stage tiles (L2-hot) and recompute distances (bit-identical) ----
  if (lane == 0) ocnt[w] = 0;
  int* op = idx + n * KK;
  unsigned long long em = 0;
  for (int st = 0; st < 4; ++st) {
    __syncthreads();
#pragma unroll
    for (int r = 0; r < 4; ++r)
      tile[r*256 + tid] = base[st*1024 + r*256 + tid];
    __syncthreads();
#pragma unroll
    for (int j = 0; j < 16; ++j) {
      float4 p = tile[j*64 + lane];
      float dot = fmaf(me.x, p.x, fmaf(me.y, p.y, me.z * p.z));
      float d = fmaxf(fmaf(-2.f, dot, me.w + p.w), 0.f);
      unsigned k = __float_as_uint(d);
      bool take = exact ? (k <= tau) : (k < tau);
      if (take) {
        int s = atomicAdd(&ocnt[w], 1);
        int m = st*1024 + j*64 + lane;
        if (s < KK) { op[s] = m; lsel[w*32 + s] = m; }
      }
      if (k == tau) em |= 1ull << (st*16 + j);
    }
  }
  if (!exact) {
    int n1 = ocnt[w];
    int need = KK - n1;
    for (int f = 0; f < need; ++f) {
      int myt = em ? (int)__builtin_ctzll(em) : 64;
      int mym = (myt < 64) ? ((myt >> 4) * 1024 + (myt & 15) * 64 + lane) : 0x7FFFFFFF;
      int g = mym;
#pragma unroll
      for (int o = 32; o; o >>= 1) g = min(g, __shfl_xor(g, o));
      if (mym == g && myt < 64) { em &= em - 1; op[n1 + f] = mym; lsel[w*32 + n1 + f] = mym; }
    }
  }

  // ---- fused stats epilogue ----
  int mi = lsel[w*32 + (lane & 31)];
  float4 p = base[mi];
  bool act = lane < 32;
  float r0 = act ? p.x - me.x : 0.f;
  float r1 = act ? p.y - me.y : 0.f;
  float r2 = act ? p.z - me.z : 0.f;
  float vals[9] = { r0, r1, r2, r0*r0, r0*r1, r0*r2, r1*r1, r1*r2, r2*r2 };
#pragma unroll
  for (int t = 0; t < 9; ++t) {
    float rs = wsum(vals[t]);
    if (lane == 0) atomicAdd(&rsum[t], rs);
  }
  float nx = act ? p.x : -INF, ny = act ? p.y : -INF, nz = act ? p.z : -INF;
#pragma unroll
  for (int o = 32; o; o >>= 1) {
    nx = fmaxf(nx, __shfl_xor(nx, o));
    ny = fmaxf(ny, __shfl_xor(ny, o));
    nz = fmaxf(nz, __shfl_xor(nz, o));
  }
  float ts = fmaf(me.x, wk0, fmaf(me.y, wk1, fmaf(me.z, wk2,
             fmaf(nx, wk3, fmaf(ny, wk4, nz * wk5)))));
  tsk[n*64 + lane] = ts;
  atomicAdd(&psum[lane], ts);
  atomicAdd(&pss[lane], ts * ts);
  __syncthreads();
  if (tid < 9)  atomicAdd(&prel9[tid], rsum[tid]);
  if (tid < 64) atomicAdd(&psk128[tid], psum[tid]);
  else if (tid < 128) atomicAdd(&psk128[tid], pss[tid - 64]);
}

// ---------------- 3: finalize BN1 (from rel moments) and BN_sk ----------------
__global__ __launch_bounds__(64,1) void k_fin1(const float* __restrict__ prel9, const float* __restrict__ psk128,
                                               const float* __restrict__ Wp1,
                                               const float* __restrict__ g_p, const float* __restrict__ b_p,
                                               const float* __restrict__ g_sk, const float* __restrict__ b_sk,
                                               float* __restrict__ aff) {
  int d = threadIdx.x;
  double C = (double)NP * (double)KK;
  double mr0 = prel9[0]/C, mr1 = prel9[1]/C, mr2 = prel9[2]/C;
  double e00 = prel9[3]/C, e01 = prel9[4]/C, e02 = prel9[5]/C;
  double e11 = prel9[6]/C, e12 = prel9[7]/C, e22 = prel9[8]/C;
  double w0 = Wp1[d*3+0], w1 = Wp1[d*3+1], w2 = Wp1[d*3+2];
  double mu  = w0*mr0 + w1*mr1 + w2*mr2;
  double ex2 = w0*w0*e00 + w1*w1*e11 + w2*w2*e22 + 2.0*(w0*w1*e01 + w0*w2*e02 + w1*w2*e12);
  double var = ex2 - mu*mu;
  double sc  = (double)g_p[d] / sqrt(var + 1e-5);
  aff[0*64 + d] = (float)sc;
  aff[1*64 + d] = (float)((double)b_p[d] - mu*sc);
  double mean = (double)psk128[d] / (double)NP;
  double v2   = (double)psk128[64+d] / (double)NP - mean*mean;
  double sc4  = (double)g_sk[d] / sqrt(v2 + 1e-5);
  aff[6*64 + d] = (float)sc4;
  aff[7*64 + d] = (float)((double)b_sk[d] - mean*sc4);
}

// ---------------- tiny finalize from 128-word global accumulator ----------------
__global__ __launch_bounds__(64,1) void k_fin2(const float* __restrict__ st, double C,
                                               const float* __restrict__ g, const float* __restrict__ b,
                                               float* __restrict__ s_out, float* __restrict__ o_out) {
  int d = threadIdx.x;
  double mean = (double)st[d] / C;
  double var  = (double)st[64 + d] / C - mean*mean;
  double sc   = (double)g[d] / sqrt(var + 1e-5);
  s_out[d] = (float)sc;
  o_out[d] = (float)((double)b[d] - mean*sc);
}

// ---------------- MFMA entry chain: MODE 0 = t_a stats; MODE 1 = softmax/agg/t_c ----------------
// round-12 proven config: 8 points/wave, 512 blocks, next-point gather prefetch.
template<int MODE>
__global__ __launch_bounds__(256,1) void k_entry(const float4* __restrict__ pts, const int* __restrict__ idx,
                                                 const float* __restrict__ Wq, const float* __restrict__ Wkv,
                                                 const float* __restrict__ Wp1, const float* __restrict__ Wp2,
                                                 const float* __restrict__ Wa, const float* __restrict__ Wc1,
                                                 const float* __restrict__ aff, float* __restrict__ pstats,
                                                 float* __restrict__ tc) {
  __shared__ __align__(16) unsigned short ybuf[4][32][72];
  __shared__ __align__(16) float aggbuf[4][64];
  __shared__ float psum[64], pss[64];
  if (threadIdx.x < 64) { psum[threadIdx.x] = 0.f; pss[threadIdx.x] = 0.f; }
  __syncthreads();
  const int lane = threadIdx.x & 63;
  const int w    = threadIdx.x >> 6;
  const int c    = lane & 31;
  const int q5   = lane >> 5;

  F8 B0[2];
#pragma unroll
  for (int nt = 0; nt < 2; ++nt)
#pragma unroll
    for (int t = 0; t < 8; ++t)
      B0[nt].us[t] = (q5 == 0 && t < 3) ? bfbits(Wp1[(nt*32+c)*3 + t]) : (unsigned short)0;

  F8 Bs[4][2], B2[4][2];
#pragma unroll
  for (int kt = 0; kt < 4; ++kt)
#pragma unroll
    for (int h = 0; h < 2; ++h) {
      const float* p2 = Wp2 + (h*32+c)*64 + kt*16 + q5*8;
      float4 a = *(const float4*)p2, b = *(const float4*)(p2 + 4);
      Bs[kt][h].us[0]=bfbits(a.x); Bs[kt][h].us[1]=bfbits(a.y); Bs[kt][h].us[2]=bfbits(a.z); Bs[kt][h].us[3]=bfbits(a.w);
      Bs[kt][h].us[4]=bfbits(b.x); Bs[kt][h].us[5]=bfbits(b.y); Bs[kt][h].us[6]=bfbits(b.z); Bs[kt][h].us[7]=bfbits(b.w);
      const float* pa = Wa + (h*32+c)*64 + kt*16 + q5*8;
      float4 e = *(const float4*)pa, f = *(const float4*)(pa + 4);
      B2[kt][h].us[0]=bfbits(e.x); B2[kt][h].us[1]=bfbits(e.y); B2[kt][h].us[2]=bfbits(e.z); B2[kt][h].us[3]=bfbits(e.w);
      B2[kt][h].us[4]=bfbits(f.x); B2[kt][h].us[5]=bfbits(f.y); B2[kt][h].us[6]=bfbits(f.z); B2[kt][h].us[7]=bfbits(f.w);
    }

  F8 Bk4[4];
#pragma unroll
  for (int nt = 0; nt < 4; ++nt) {
    if (MODE == 0 && nt >= 2) { for (int t = 0; t < 8; ++t) Bk4[nt].us[t] = 0; continue; }
    int e = (nt & 1)*32 + c;
#pragma unroll
    for (int t = 0; t < 8; ++t)
      Bk4[nt].us[t] = (q5 == 0 && t < 3)
        ? bfbits(nt < 2 ? -Wkv[e*3 + t] : Wkv[(64+e)*3 + t]) : (unsigned short)0;
  }

  const float s1a = aff[c],      o1a = aff[64+c];
  const float s1b = aff[32+c],   o1b = aff[96+c];
  float s2a = 0.f, o2a = 0.f, s2b = 0.f, o2b = 0.f;
  if (MODE == 1) { s2a = aff[128+c]; o2a = aff[192+c]; s2b = aff[160+c]; o2b = aff[224+c]; }
  const float wqa0 = Wq[c*3+0],      wqa1 = Wq[c*3+1],      wqa2 = Wq[c*3+2];
  const float wqb0 = Wq[(32+c)*3+0], wqb1 = Wq[(32+c)*3+1], wqb2 = Wq[(32+c)*3+2];

  const int wave_id = blockIdx.x * 4 + w;
  const int n0 = wave_id * 8;
  const int batch = n0 >> 12;
  const float4* base = pts + batch * NPTS;

  // prefetch point 0's gather
  float4 me = pts[n0];
  float4 pp = base[idx[n0*KK + c]];

  for (int pi = 0; pi < 8; ++pi) {
    const int n = n0 + pi;
    // issue next point's gather before this point's compute chain
    float4 men = me, ppn = pp;
    if (pi < 7) {
      men = pts[n + 1];
      ppn = base[idx[(n + 1)*KK + c]];
    }
    const float r0 = pp.x - me.x, r1 = pp.y - me.y, r2 = pp.z - me.z;
    F8 relA;
#pragma unroll
    for (int t = 0; t < 8; ++t) relA.us[t] = 0;
    if (q5 == 0) { relA.us[0] = bfbits(r0); relA.us[1] = bfbits(r1); relA.us[2] = bfbits(r2); }

    const floatx16 z = zero16();
    floatx16 y0 = MFMA32(relA.v, B0[0].v, z);
    floatx16 y1 = MFMA32(relA.v, B0[1].v, z);
#pragma unroll
    for (int r = 0; r < 16; ++r) {
      int row = (r & 3) + 8*(r >> 2) + 4*q5;
      ybuf[w][row][c]      = bfbits(fmaxf(fmaf(y0[r], s1a, o1a), 0.f));
      ybuf[w][row][32 + c] = bfbits(fmaxf(fmaf(y1[r], s1b, o1b), 0.f));
    }
    F8 Ay[4];
#pragma unroll
    for (int kt = 0; kt < 4; ++kt) Ay[kt].q4 = *(const uint4*)&ybuf[w][c][kt*16 + q5*8];

    floatx16 Cp0 = z, Cp1 = z;
#pragma unroll
    for (int kt = 0; kt < 4; ++kt) {
      Cp0 = MFMA32(Ay[kt].v, Bs[kt][0].v, Cp0);
      Cp1 = MFMA32(Ay[kt].v, Bs[kt][1].v, Cp1);
    }
    floatx16 Cu0 = MFMA32(relA.v, Bk4[0].v, Cp0);
    floatx16 Cu1 = MFMA32(relA.v, Bk4[1].v, Cp1);
    if (MODE == 1) {
      Cp0 = MFMA32(relA.v, Bk4[2].v, Cp0);
      Cp1 = MFMA32(relA.v, Bk4[3].v, Cp1);
    }
    const float qa = fmaf(me.x, wqa0, fmaf(me.y, wqa1, me.z * wqa2));
    const float qb = fmaf(me.x, wqb0, fmaf(me.y, wqb1, me.z * wqb2));
#pragma unroll
    for (int r = 0; r < 16; ++r) {
      int row = (r & 3) + 8*(r >> 2) + 4*q5;
      ybuf[w][row][c]      = bfbits(Cu0[r] + qa);
      ybuf[w][row][32 + c] = bfbits(Cu1[r] + qb);
    }
    F8 Au[4];
#pragma unroll
    for (int kt = 0; kt < 4; ++kt) Au[kt].q4 = *(const uint4*)&ybuf[w][c][kt*16 + q5*8];
    floatx16 Ct0 = z, Ct1 = z;
#pragma unroll
    for (int kt = 0; kt < 4; ++kt) {
      Ct0 = MFMA32(Au[kt].v, B2[kt][0].v, Ct0);
      Ct1 = MFMA32(Au[kt].v, B2[kt][1].v, Ct1);
    }

    if (MODE == 0) {
      float sa = 0.f, qqa = 0.f, sb = 0.f, qqb = 0.f;
#pragma unroll
      for (int r = 0; r < 16; ++r) {
        sa += Ct0[r]; qqa = fmaf(Ct0[r], Ct0[r], qqa);
        sb += Ct1[r]; qqb = fmaf(Ct1[r], Ct1[r], qqb);
      }
      sa += __shfl_xor(sa, 32); qqa += __shfl_xor(qqa, 32);
      sb += __shfl_xor(sb, 32); qqb += __shfl_xor(qqb, 32);
      if (q5 == 0) {
        atomicAdd(&psum[c], sa);      atomicAdd(&pss[c], qqa);
        atomicAdd(&psum[32+c], sb);   atomicAdd(&pss[32+c], qqb);
      }
    } else {
      float ma = -INF, mb = -INF;
#pragma unroll
      for (int r = 0; r < 16; ++r) {
        float la = fmaxf(fmaf(Ct0[r], s2a, o2a), 0.f); Ct0[r] = la; ma = fmaxf(ma, la);
        float lb = fmaxf(fmaf(Ct1[r], s2b, o2b), 0.f); Ct1[r] = lb; mb = fmaxf(mb, lb);
      }
      ma = fmaxf(ma, __shfl_xor(ma, 32));
      mb = fmaxf(mb, __shfl_xor(mb, 32));
      float sa = 0.f, sb = 0.f, aga = 0.f, agb = 0.f;
#pragma unroll
      for (int r = 0; r < 16; ++r) {
        float ta = __expf(Ct0[r] - ma); sa += ta; aga = fmaf(ta, Cp0[r], aga);
        float tb = __expf(Ct1[r] - mb); sb += tb; agb = fmaf(tb, Cp1[r], agb);
      }
      sa += __shfl_xor(sa, 32); aga += __shfl_xor(aga, 32);
      sb += __shfl_xor(sb, 32); agb += __shfl_xor(agb, 32);
      if (q5 == 0) {
        aggbuf[w][c]      = aga / sa;
        aggbuf[w][32 + c] = agb / sb;
      }
      float acc = 0.f;
#pragma unroll
      for (int g = 0; g < 16; ++g) {
        float4 av = *(const float4*)&aggbuf[w][g*4];
        const float4 wv = *(const float4*)(Wc1 + lane*64 + g*4);
        acc = fmaf(av.x, wv.x, fmaf(av.y, wv.y, fmaf(av.z, wv.z, fmaf(av.w, wv.w, acc))));
      }
      tc[n*64 + lane] = acc;
      atomicAdd(&psum[lane], acc);
      atomicAdd(&pss[lane], acc * acc);
    }
    me = men; pp = ppn;
  }
  __syncthreads();
  if (threadIdx.x < 64) atomicAdd(&pstats[threadIdx.x], psum[threadIdx.x]);
  else if (threadIdx.x < 128) atomicAdd(&pstats[threadIdx.x], pss[threadIdx.x - 64]);
}

// ---------------- t_ga = concat(h, sk) @ Wga^T + its stats ----------------
__global__ __launch_bounds__(256,1) void k_final(const float* __restrict__ tcb, const float* __restrict__ tskb,
                                                 const float* __restrict__ Wga, const float* __restrict__ aff,
                                                 float* __restrict__ tga, float* __restrict__ pstats) {
  __shared__ __align__(16) float hb[4][64];
  __shared__ __align__(16) float sb[4][64];
  __shared__ float psum[64], pss[64];
  if (threadIdx.x < 64) { psum[threadIdx.x] = 0.f; pss[threadIdx.x] = 0.f; }
  __syncthreads();
  const int lane = threadIdx.x & 63;
  const int w    = threadIdx.x >> 6;
  const int n = blockIdx.x * 4 + w;
  hb[w][lane] = fmaxf(fmaf(tcb[n*64 + lane],  aff[256 + lane], aff[320 + lane]), 0.f);
  sb[w][lane] = fmaxf(fmaf(tskb[n*64 + lane], aff[384 + lane], aff[448 + lane]), 0.f);
  float g0=0,g1=0,g2=0,g3=0;
#pragma unroll
  for (int d = 0; d < 64; d += 4) {
    const float4 hv = *(const float4*)&hb[w][d];
    const float4 wg = *(const float4*)(Wga + lane*128 + d);
    g0 = fmaf(hv.x, wg.x, g0);
    g1 = fmaf(hv.y, wg.y, g1);
    g2 = fmaf(hv.z, wg.z, g2);
    g3 = fmaf(hv.w, wg.w, g3);
  }
#pragma unroll
  for (int d = 0; d < 64; d += 4) {
    const float4 sv = *(const float4*)&sb[w][d];
    const float4 wg = *(const float4*)(Wga + lane*128 + 64 + d);
    g0 = fmaf(sv.x, wg.x, g0);
    g1 = fmaf(sv.y, wg.y, g1);
    g2 = fmaf(sv.z, wg.z, g2);
    g3 = fmaf(sv.w, wg.w, g3);
  }
  const float tg = (g0+g1) + (g2+g3);
  tga[n*64 + lane] = tg;
  atomicAdd(&psum[lane], tg);
  atomicAdd(&pss[lane], tg * tg);
  __syncthreads();
  if (threadIdx.x < 64) atomicAdd(&pstats[threadIdx.x], psum[threadIdx.x]);
  else if (threadIdx.x < 128) atomicAdd(&pstats[threadIdx.x], pss[threadIdx.x - 64]);
}

// ---------------- output: relu(BN5) + transpose to (B,64,N) ----------------
__global__ __launch_bounds__(256,1) void k_out(const float* __restrict__ tga, const float* __restrict__ aff,
                                               float* __restrict__ out) {
  int g = blockIdx.x * 256 + threadIdx.x;
  int nn = g & 4095;
  int e  = (g >> 12) & 63;
  int b  = g >> 18;
  float v = tga[((b << 12) + nn) * 64 + e];
  out[g] = fmaxf(fmaf(v, aff[512 + e], aff[576 + e]), 0.f);
}

extern "C" void kernel_launch(void* const* d_in, const int* in_sizes, int n_in,
                              void* d_out, int out_size, void* d_ws, size_t ws_size,
                              hipStream_t stream) {
  const float* x    = (const float*)d_in[0];
  const float* Wq   = (const float*)d_in[1];
  const float* Wkv  = (const float*)d_in[2];
  const float* Wp1  = (const float*)d_in[3];
  const float* Wp2  = (const float*)d_in[4];
  const float* Wa   = (const float*)d_in[5];
  const float* Wc1  = (const float*)d_in[6];
  const float* Wsk  = (const float*)d_in[7];
  const float* Wga  = (const float*)d_in[8];
  const float* g_p  = (const float*)d_in[9];
  const float* b_p  = (const float*)d_in[10];
  const float* g_a  = (const float*)d_in[11];
  const float* b_a  = (const float*)d_in[12];
  const float* g_c  = (const float*)d_in[13];
  const float* b_c  = (const float*)d_in[14];
  const float* g_sk = (const float*)d_in[15];
  const float* b_sk = (const float*)d_in[16];
  const float* g_ga = (const float*)d_in[17];
  const float* b_ga = (const float*)d_in[18];
  float* W = (float*)d_ws;
  float4*  pts   = (float4*)(W + OFF_PTS);
  int*     idx   = (int*)(W + OFF_IDX);
  float*   tsk   = W + OFF_TSK;
  float*   tc    = W + OFF_TC;
  float*   tga   = W + OFF_TGA;
  float*   prel9 = W + OFF_PREL;
  float*   psk   = W + OFF_PSK;
  float*   pta   = W + OFF_PTA;
  float*   ptc   = W + OFF_PTC;
  float*   ptga  = W + OFF_PTGA;
  float*   aff   = W + OFF_AFF;
  float*   out   = (float*)d_out;

  k_prep<<<64, 256, 0, stream>>>(x, pts, pta, ptc, ptga, prel9, psk);
  k_knn<<<4096, 256, 0, stream>>>(pts, idx, Wsk, tsk, prel9, psk);
  k_fin1<<<1, 64, 0, stream>>>(prel9, psk, Wp1, g_p, b_p, g_sk, b_sk, aff);
  k_entry<0><<<512, 256, 0, stream>>>(pts, idx, Wq, Wkv, Wp1, Wp2, Wa, nullptr, aff, pta, nullptr);
  k_fin2<<<1, 64, 0, stream>>>(pta, (double)NP * (double)KK, g_a, b_a, aff + 128, aff + 192);
  k_entry<1><<<512, 256, 0, stream>>>(pts, idx, Wq, Wkv, Wp1, Wp2, Wa, Wc1, aff, ptc, tc);
  k_fin2<<<1, 64, 0, stream>>>(ptc, (double)NP, g_c, b_c, aff + 256, aff + 320);
  k_final<<<4096, 256, 0, stream>>>(tc, tsk, Wga, aff, tga, ptga);
  k_fin2<<<1, 64, 0, stream>>>(ptga, (double)NP, g_ga, b_ga, aff + 512, aff + 576);
  k_out<<<4096, 256, 0, stream>>>(tga, aff, out);
}

// Round 15
// 465.694 us; speedup vs baseline: 1.2084x; 1.1738x over previous
//
#include <hip/hip_runtime.h>

#define NBATCH 4
#define NPTS   4096
#define NP     (NBATCH*NPTS)   // 16384
#define KK     32
#define INF    __builtin_inff()

// ---------------- ws layout (float units) ----------------
static const size_t OFF_PTS  = 0;         // float4[NP]        65536
static const size_t OFF_IDX  = 65536;     // int[NP*32]       524288
static const size_t OFF_TSK  = 589824;    // float[NP*64]    1048576
static const size_t OFF_TC   = 1638400;   // float[NP*64]
static const size_t OFF_TGA  = 2686976;   // float[NP*64]
static const size_t OFF_PREL = 3735552;   // float[9] (pad 16)
static const size_t OFF_PSK  = 3735568;   // float[128]
static const size_t OFF_PTA  = 3735696;   // float[128]
static const size_t OFF_PTC  = 3735824;   // float[128]
static const size_t OFF_PTGA = 3735952;   // float[128]
static const size_t OFF_AFF  = 3736080;   // float[640]  -> ~15 MB total

typedef __bf16 bf16x8  __attribute__((ext_vector_type(8)));
typedef float  floatx16 __attribute__((ext_vector_type(16)));
#define MFMA32(a,b,c) __builtin_amdgcn_mfma_f32_32x32x16_bf16(a, b, c, 0, 0, 0)

union F8 { bf16x8 v; unsigned short us[8]; uint4 q4; };

__device__ __forceinline__ unsigned short bfbits(float f) {
  unsigned u = __float_as_uint(f);
  return (unsigned short)((u + 0x7FFFu + ((u >> 16) & 1u)) >> 16);
}
__device__ __forceinline__ floatx16 zero16() {
  floatx16 v;
#pragma unroll
  for (int i = 0; i < 16; ++i) v[i] = 0.f;
  return v;
}
__device__ __forceinline__ float wsum(float v) {
#pragma unroll
  for (int o = 32; o; o >>= 1) v += __shfl_xor(v, o, 64);
  return v;
}
__device__ __forceinline__ int isum(int v) {
#pragma unroll
  for (int o = 32; o; o >>= 1) v += __shfl_xor(v, o);
  return v;
}

// ---------------- 1: pts4 = (x,y,z,|p|^2) + zero all stat accumulators ----------------
__global__ __launch_bounds__(256,1) void k_prep(const float* __restrict__ x, float4* __restrict__ pts,
                                                float* __restrict__ pta, float* __restrict__ ptc,
                                                float* __restrict__ ptga, float* __restrict__ prel9,
                                                float* __restrict__ psk128) {
  if (blockIdx.x == 0) {
    if (threadIdx.x < 128) {
      pta[threadIdx.x] = 0.f; ptc[threadIdx.x] = 0.f; ptga[threadIdx.x] = 0.f;
      psk128[threadIdx.x] = 0.f;
    }
    if (threadIdx.x < 16) prel9[threadIdx.x] = 0.f;
  }
  int g = blockIdx.x * 256 + threadIdx.x;
  int b = g / NPTS, n = g % NPTS;
  float vx = x[(b*3+0)*NPTS + n];
  float vy = x[(b*3+1)*NPTS + n];
  float vz = x[(b*3+2)*NPTS + n];
  pts[g] = make_float4(vx, vy, vz, vx*vx + vy*vy + vz*vz);
}

// ---------------- 2: kNN (top-4 prefilter + narrow bisect + exact fallback) + fused stats ----------------
// round-12 structure with DOUBLE-BUFFERED tile staging (1 barrier/stage, loads overlapped).
__global__ __launch_bounds__(256) void k_knn(const float4* __restrict__ pts, int* __restrict__ idx,
                                             const float* __restrict__ Wsk, float* __restrict__ tsk,
                                             float* __restrict__ prel9, float* __restrict__ psk128) {
  __shared__ __align__(16) float4 tile[2][1024];   // 32 KB double buffer
  __shared__ int ocnt[4];
  __shared__ int lsel[128];                      // selected indices, per wave
  __shared__ float rsum[9], psum[64], pss[64];
  const int tid  = threadIdx.x;
  const int w    = tid >> 6;
  const int lane = tid & 63;
  if (tid < 9)  rsum[tid] = 0.f;
  if (tid < 64) { psum[tid] = 0.f; pss[tid] = 0.f; }
  const int n = blockIdx.x * 4 + w;
  const int batch = n >> 12;
  const float4* base = pts + batch * NPTS;
  const float4 me = pts[n];
  const float wk0 = Wsk[lane*6+0], wk1 = Wsk[lane*6+1], wk2 = Wsk[lane*6+2],
              wk3 = Wsk[lane*6+3], wk4 = Wsk[lane*6+4], wk5 = Wsk[lane*6+5];

  unsigned keys[64];
  unsigned t0 = 0xFFFFFFFFu, t1 = 0xFFFFFFFFu, t2 = 0xFFFFFFFFu, t3 = 0xFFFFFFFFu;

  // prologue: stage 0 into buffer 0
  {
    float4 pre0 = base[0*256 + tid], pre1 = base[1*256 + tid],
           pre2 = base[2*256 + tid], pre3 = base[3*256 + tid];
    tile[0][0*256 + tid] = pre0; tile[0][1*256 + tid] = pre1;
    tile[0][2*256 + tid] = pre2; tile[0][3*256 + tid] = pre3;
  }
  __syncthreads();
  for (int st = 0; st < 4; ++st) {
    float4 pre0, pre1, pre2, pre3;
    if (st < 3) {                      // issue next stage's loads (overlap with compute)
      const float4* nb = base + (st + 1) * 1024;
      pre0 = nb[0*256 + tid]; pre1 = nb[1*256 + tid];
      pre2 = nb[2*256 + tid]; pre3 = nb[3*256 + tid];
    }
    const float4* tb = tile[st & 1];
#pragma unroll
    for (int j = 0; j < 16; ++j) {
      float4 p = tb[j*64 + lane];
      float dot = fmaf(me.x, p.x, fmaf(me.y, p.y, me.z * p.z));
      float d = fmaxf(fmaf(-2.f, dot, me.w + p.w), 0.f);
      unsigned k = __float_as_uint(d);           // positive floats order as uints
      keys[st*16 + j] = k;
      unsigned m = k, x;
      x = min(t0, m); m = max(t0, m); t0 = x;
      x = min(t1, m); m = max(t1, m); t1 = x;
      x = min(t2, m); m = max(t2, m); t2 = x;
      t3 = min(t3, m);
    }
    if (st < 3) {
      float4* nt = tile[(st + 1) & 1];
      nt[0*256 + tid] = pre0; nt[1*256 + tid] = pre1;
      nt[2*256 + tid] = pre2; nt[3*256 + tid] = pre3;
      __syncthreads();
    }
  }

  // ---- wave bounds: tau in [min(t0), max(t3)] ----
  unsigned glo = t0, ghi = t3;
#pragma unroll
  for (int o = 32; o; o >>= 1) {
    glo = min(glo, (unsigned)__shfl_xor((int)glo, o));
    ghi = max(ghi, (unsigned)__shfl_xor((int)ghi, o));
  }

  // ---- narrow bisect over per-lane top-4 ----
  unsigned lo = glo, hi = ghi, tau = ghi;
  bool exact = false;
  while (lo < hi) {
    unsigned mid = lo + ((hi - lo) >> 1);
    int c = (t0 <= mid) + (t1 <= mid) + (t2 <= mid) + (t3 <= mid);
    c = isum(c);
    if (c == 32) { tau = mid; exact = true; break; }
    if (c > 32) hi = mid; else lo = mid + 1;
  }
  if (!exact) tau = lo;

  // ---- validity: every key <= tau must be inside some lane's kept-4 ----
  if (__ballot(t3 <= tau) != 0ull) {
    lo = glo; hi = tau; exact = false;           // full fallback on narrowed range
    while (lo < hi) {
      unsigned mid = lo + ((hi - lo) >> 1);
      int c = 0;
#pragma unroll
      for (int t = 0; t < 64; ++t) c += (keys[t] <= mid) ? 1 : 0;
      c = isum(c);
      if (c == 32) { tau = mid; exact = true; break; }
      if (c > 32) hi = mid; else lo = mid + 1;
    }
    if (!exact) tau = lo;
  }

  // ---- collect (order irrelevant downstream; ties filled by min index) ----
  if (lane == 0) ocnt[w] = 0;
  int* op = idx + n * KK;
#pragma unroll
  for (int t = 0; t < 64; ++t) {
    bool take = exact ? (keys[t] <= tau) : (keys[t] < tau);
    if (take) {
      int s = atomicAdd(&ocnt[w], 1);
      int m = (t >> 4) * 1024 + (t & 15) * 64 + lane;
      op[s] = m; lsel[w*32 + s] = m;
    }
  }
  if (!exact) {
    unsigned long long em = 0;
#pragma unroll
    for (int t = 0; t < 64; ++t) if (keys[t] == tau) em |= 1ull << t;
    int n1 = ocnt[w];
    int need = 32 - n1;
    for (int f = 0; f < need; ++f) {
      int myt = em ? (int)__builtin_ctzll(em) : 64;
      int mym = (myt < 64) ? ((myt >> 4) * 1024 + (myt & 15) * 64 + lane) : 0x7FFFFFFF;
      int g = mym;
#pragma unroll
      for (int o = 32; o; o >>= 1) g = min(g, __shfl_xor(g, o));
      if (mym == g && myt < 64) { em &= em - 1; op[n1 + f] = mym; lsel[w*32 + n1 + f] = mym; }
    }
  }

  // ---- fused stats epilogue ----
  int mi = lsel[w*32 + (lane & 31)];
  float4 p = base[mi];
  bool act = lane < 32;
  float r0 = act ? p.x - me.x : 0.f;
  float r1 = act ? p.y - me.y : 0.f;
  float r2 = act ? p.z - me.z : 0.f;
  float vals[9] = { r0, r1, r2, r0*r0, r0*r1, r0*r2, r1*r1, r1*r2, r2*r2 };
#pragma unroll
  for (int t = 0; t < 9; ++t) {
    float rs = wsum(vals[t]);
    if (lane == 0) atomicAdd(&rsum[t], rs);
  }
  float nx = act ? p.x : -INF, ny = act ? p.y : -INF, nz = act ? p.z : -INF;
#pragma unroll
  for (int o = 32; o; o >>= 1) {
    nx = fmaxf(nx, __shfl_xor(nx, o));
    ny = fmaxf(ny, __shfl_xor(ny, o));
    nz = fmaxf(nz, __shfl_xor(nz, o));
  }
  float ts = fmaf(me.x, wk0, fmaf(me.y, wk1, fmaf(me.z, wk2,
             fmaf(nx, wk3, fmaf(ny, wk4, nz * wk5)))));
  tsk[n*64 + lane] = ts;
  atomicAdd(&psum[lane], ts);
  atomicAdd(&pss[lane], ts * ts);
  __syncthreads();
  if (tid < 9)  atomicAdd(&prel9[tid], rsum[tid]);
  if (tid < 64) atomicAdd(&psk128[tid], psum[tid]);
  else if (tid < 128) atomicAdd(&psk128[tid], pss[tid - 64]);
}

// ---------------- 3: finalize BN1 (from rel moments) and BN_sk ----------------
__global__ __launch_bounds__(64,1) void k_fin1(const float* __restrict__ prel9, const float* __restrict__ psk128,
                                               const float* __restrict__ Wp1,
                                               const float* __restrict__ g_p, const float* __restrict__ b_p,
                                               const float* __restrict__ g_sk, const float* __restrict__ b_sk,
                                               float* __restrict__ aff) {
  int d = threadIdx.x;
  double C = (double)NP * (double)KK;
  double mr0 = prel9[0]/C, mr1 = prel9[1]/C, mr2 = prel9[2]/C;
  double e00 = prel9[3]/C, e01 = prel9[4]/C, e02 = prel9[5]/C;
  double e11 = prel9[6]/C, e12 = prel9[7]/C, e22 = prel9[8]/C;
  double w0 = Wp1[d*3+0], w1 = Wp1[d*3+1], w2 = Wp1[d*3+2];
  double mu  = w0*mr0 + w1*mr1 + w2*mr2;
  double ex2 = w0*w0*e00 + w1*w1*e11 + w2*w2*e22 + 2.0*(w0*w1*e01 + w0*w2*e02 + w1*w2*e12);
  double var = ex2 - mu*mu;
  double sc  = (double)g_p[d] / sqrt(var + 1e-5);
  aff[0*64 + d] = (float)sc;
  aff[1*64 + d] = (float)((double)b_p[d] - mu*sc);
  double mean = (double)psk128[d] / (double)NP;
  double v2   = (double)psk128[64+d] / (double)NP - mean*mean;
  double sc4  = (double)g_sk[d] / sqrt(v2 + 1e-5);
  aff[6*64 + d] = (float)sc4;
  aff[7*64 + d] = (float)((double)b_sk[d] - mean*sc4);
}

// ---------------- tiny finalize from 128-word global accumulator ----------------
__global__ __launch_bounds__(64,1) void k_fin2(const float* __restrict__ st, double C,
                                               const float* __restrict__ g, const float* __restrict__ b,
                                               float* __restrict__ s_out, float* __restrict__ o_out) {
  int d = threadIdx.x;
  double mean = (double)st[d] / C;
  double var  = (double)st[64 + d] / C - mean*mean;
  double sc   = (double)g[d] / sqrt(var + 1e-5);
  s_out[d] = (float)sc;
  o_out[d] = (float)((double)b[d] - mean*sc);
}

// ---------------- MFMA entry chain: MODE 0 = t_a stats; MODE 1 = softmax/agg/t_c ----------------
// round-12 proven config: 8 points/wave, 512 blocks, next-point gather prefetch.
template<int MODE>
__global__ __launch_bounds__(256,1) void k_entry(const float4* __restrict__ pts, const int* __restrict__ idx,
                                                 const float* __restrict__ Wq, const float* __restrict__ Wkv,
                                                 const float* __restrict__ Wp1, const float* __restrict__ Wp2,
                                                 const float* __restrict__ Wa, const float* __restrict__ Wc1,
                                                 const float* __restrict__ aff, float* __restrict__ pstats,
                                                 float* __restrict__ tc) {
  __shared__ __align__(16) unsigned short ybuf[4][32][72];
  __shared__ __align__(16) float aggbuf[4][64];
  __shared__ float psum[64], pss[64];
  if (threadIdx.x < 64) { psum[threadIdx.x] = 0.f; pss[threadIdx.x] = 0.f; }
  __syncthreads();
  const int lane = threadIdx.x & 63;
  const int w    = threadIdx.x >> 6;
  const int c    = lane & 31;
  const int q5   = lane >> 5;

  F8 B0[2];
#pragma unroll
  for (int nt = 0; nt < 2; ++nt)
#pragma unroll
    for (int t = 0; t < 8; ++t)
      B0[nt].us[t] = (q5 == 0 && t < 3) ? bfbits(Wp1[(nt*32+c)*3 + t]) : (unsigned short)0;

  F8 Bs[4][2], B2[4][2];
#pragma unroll
  for (int kt = 0; kt < 4; ++kt)
#pragma unroll
    for (int h = 0; h < 2; ++h) {
      const float* p2 = Wp2 + (h*32+c)*64 + kt*16 + q5*8;
      float4 a = *(const float4*)p2, b = *(const float4*)(p2 + 4);
      Bs[kt][h].us[0]=bfbits(a.x); Bs[kt][h].us[1]=bfbits(a.y); Bs[kt][h].us[2]=bfbits(a.z); Bs[kt][h].us[3]=bfbits(a.w);
      Bs[kt][h].us[4]=bfbits(b.x); Bs[kt][h].us[5]=bfbits(b.y); Bs[kt][h].us[6]=bfbits(b.z); Bs[kt][h].us[7]=bfbits(b.w);
      const float* pa = Wa + (h*32+c)*64 + kt*16 + q5*8;
      float4 e = *(const float4*)pa, f = *(const float4*)(pa + 4);
      B2[kt][h].us[0]=bfbits(e.x); B2[kt][h].us[1]=bfbits(e.y); B2[kt][h].us[2]=bfbits(e.z); B2[kt][h].us[3]=bfbits(e.w);
      B2[kt][h].us[4]=bfbits(f.x); B2[kt][h].us[5]=bfbits(f.y); B2[kt][h].us[6]=bfbits(f.z); B2[kt][h].us[7]=bfbits(f.w);
    }

  F8 Bk4[4];
#pragma unroll
  for (int nt = 0; nt < 4; ++nt) {
    if (MODE == 0 && nt >= 2) { for (int t = 0; t < 8; ++t) Bk4[nt].us[t] = 0; continue; }
    int e = (nt & 1)*32 + c;
#pragma unroll
    for (int t = 0; t < 8; ++t)
      Bk4[nt].us[t] = (q5 == 0 && t < 3)
        ? bfbits(nt < 2 ? -Wkv[e*3 + t] : Wkv[(64+e)*3 + t]) : (unsigned short)0;
  }

  const float s1a = aff[c],      o1a = aff[64+c];
  const float s1b = aff[32+c],   o1b = aff[96+c];
  float s2a = 0.f, o2a = 0.f, s2b = 0.f, o2b = 0.f;
  if (MODE == 1) { s2a = aff[128+c]; o2a = aff[192+c]; s2b = aff[160+c]; o2b = aff[224+c]; }
  const float wqa0 = Wq[c*3+0],      wqa1 = Wq[c*3+1],      wqa2 = Wq[c*3+2];
  const float wqb0 = Wq[(32+c)*3+0], wqb1 = Wq[(32+c)*3+1], wqb2 = Wq[(32+c)*3+2];

  const int wave_id = blockIdx.x * 4 + w;
  const int n0 = wave_id * 8;
  const int batch = n0 >> 12;
  const float4* base = pts + batch * NPTS;

  // prefetch point 0's gather
  float4 me = pts[n0];
  float4 pp = base[idx[n0*KK + c]];

  for (int pi = 0; pi < 8; ++pi) {
    const int n = n0 + pi;
    // issue next point's gather before this point's compute chain
    float4 men = me, ppn = pp;
    if (pi < 7) {
      men = pts[n + 1];
      ppn = base[idx[(n + 1)*KK + c]];
    }
    const float r0 = pp.x - me.x, r1 = pp.y - me.y, r2 = pp.z - me.z;
    F8 relA;
#pragma unroll
    for (int t = 0; t < 8; ++t) relA.us[t] = 0;
    if (q5 == 0) { relA.us[0] = bfbits(r0); relA.us[1] = bfbits(r1); relA.us[2] = bfbits(r2); }

    const floatx16 z = zero16();
    floatx16 y0 = MFMA32(relA.v, B0[0].v, z);
    floatx16 y1 = MFMA32(relA.v, B0[1].v, z);
#pragma unroll
    for (int r = 0; r < 16; ++r) {
      int row = (r & 3) + 8*(r >> 2) + 4*q5;
      ybuf[w][row][c]      = bfbits(fmaxf(fmaf(y0[r], s1a, o1a), 0.f));
      ybuf[w][row][32 + c] = bfbits(fmaxf(fmaf(y1[r], s1b, o1b), 0.f));
    }
    F8 Ay[4];
#pragma unroll
    for (int kt = 0; kt < 4; ++kt) Ay[kt].q4 = *(const uint4*)&ybuf[w][c][kt*16 + q5*8];

    floatx16 Cp0 = z, Cp1 = z;
#pragma unroll
    for (int kt = 0; kt < 4; ++kt) {
      Cp0 = MFMA32(Ay[kt].v, Bs[kt][0].v, Cp0);
      Cp1 = MFMA32(Ay[kt].v, Bs[kt][1].v, Cp1);
    }
    floatx16 Cu0 = MFMA32(relA.v, Bk4[0].v, Cp0);
    floatx16 Cu1 = MFMA32(relA.v, Bk4[1].v, Cp1);
    if (MODE == 1) {
      Cp0 = MFMA32(relA.v, Bk4[2].v, Cp0);
      Cp1 = MFMA32(relA.v, Bk4[3].v, Cp1);
    }
    const float qa = fmaf(me.x, wqa0, fmaf(me.y, wqa1, me.z * wqa2));
    const float qb = fmaf(me.x, wqb0, fmaf(me.y, wqb1, me.z * wqb2));
#pragma unroll
    for (int r = 0; r < 16; ++r) {
      int row = (r & 3) + 8*(r >> 2) + 4*q5;
      ybuf[w][row][c]      = bfbits(Cu0[r] + qa);
      ybuf[w][row][32 + c] = bfbits(Cu1[r] + qb);
    }
    F8 Au[4];
#pragma unroll
    for (int kt = 0; kt < 4; ++kt) Au[kt].q4 = *(const uint4*)&ybuf[w][c][kt*16 + q5*8];
    floatx16 Ct0 = z, Ct1 = z;
#pragma unroll
    for (int kt = 0; kt < 4; ++kt) {
      Ct0 = MFMA32(Au[kt].v, B2[kt][0].v, Ct0);
      Ct1 = MFMA32(Au[kt].v, B2[kt][1].v, Ct1);
    }

    if (MODE == 0) {
      float sa = 0.f, qqa = 0.f, sb = 0.f, qqb = 0.f;
#pragma unroll
      for (int r = 0; r < 16; ++r) {
        sa += Ct0[r]; qqa = fmaf(Ct0[r], Ct0[r], qqa);
        sb += Ct1[r]; qqb = fmaf(Ct1[r], Ct1[r], qqb);
      }
      sa += __shfl_xor(sa, 32); qqa += __shfl_xor(qqa, 32);
      sb += __shfl_xor(sb, 32); qqb += __shfl_xor(qqb, 32);
      if (q5 == 0) {
        atomicAdd(&psum[c], sa);      atomicAdd(&pss[c], qqa);
        atomicAdd(&psum[32+c], sb);   atomicAdd(&pss[32+c], qqb);
      }
    } else {
      float ma = -INF, mb = -INF;
#pragma unroll
      for (int r = 0; r < 16; ++r) {
        float la = fmaxf(fmaf(Ct0[r], s2a, o2a), 0.f); Ct0[r] = la; ma = fmaxf(ma, la);
        float lb = fmaxf(fmaf(Ct1[r], s2b, o2b), 0.f); Ct1[r] = lb; mb = fmaxf(mb, lb);
      }
      ma = fmaxf(ma, __shfl_xor(ma, 32));
      mb = fmaxf(mb, __shfl_xor(mb, 32));
      float sa = 0.f, sb = 0.f, aga = 0.f, agb = 0.f;
#pragma unroll
      for (int r = 0; r < 16; ++r) {
        float ta = __expf(Ct0[r] - ma); sa += ta; aga = fmaf(ta, Cp0[r], aga);
        float tb = __expf(Ct1[r] - mb); sb += tb; agb = fmaf(tb, Cp1[r], agb);
      }
      sa += __shfl_xor(sa, 32); aga += __shfl_xor(aga, 32);
      sb += __shfl_xor(sb, 32); agb += __shfl_xor(agb, 32);
      if (q5 == 0) {
        aggbuf[w][c]      = aga / sa;
        aggbuf[w][32 + c] = agb / sb;
      }
      float acc = 0.f;
#pragma unroll
      for (int g = 0; g < 16; ++g) {
        float4 av = *(const float4*)&aggbuf[w][g*4];
        const float4 wv = *(const float4*)(Wc1 + lane*64 + g*4);
        acc = fmaf(av.x, wv.x, fmaf(av.y, wv.y, fmaf(av.z, wv.z, fmaf(av.w, wv.w, acc))));
      }
      tc[n*64 + lane] = acc;
      atomicAdd(&psum[lane], acc);
      atomicAdd(&pss[lane], acc * acc);
    }
    me = men; pp = ppn;
  }
  __syncthreads();
  if (threadIdx.x < 64) atomicAdd(&pstats[threadIdx.x], psum[threadIdx.x]);
  else if (threadIdx.x < 128) atomicAdd(&pstats[threadIdx.x], pss[threadIdx.x - 64]);
}

// ---------------- t_ga = concat(h, sk) @ Wga^T + its stats ----------------
__global__ __launch_bounds__(256,1) void k_final(const float* __restrict__ tcb, const float* __restrict__ tskb,
                                                 const float* __restrict__ Wga, const float* __restrict__ aff,
                                                 float* __restrict__ tga, float* __restrict__ pstats) {
  __shared__ __align__(16) float hb[4][64];
  __shared__ __align__(16) float sb[4][64];
  __shared__ float psum[64], pss[64];
  if (threadIdx.x < 64) { psum[threadIdx.x] = 0.f; pss[threadIdx.x] = 0.f; }
  __syncthreads();
  const int lane = threadIdx.x & 63;
  const int w    = threadIdx.x >> 6;
  const int n = blockIdx.x * 4 + w;
  hb[w][lane] = fmaxf(fmaf(tcb[n*64 + lane],  aff[256 + lane], aff[320 + lane]), 0.f);
  sb[w][lane] = fmaxf(fmaf(tskb[n*64 + lane], aff[384 + lane], aff[448 + lane]), 0.f);
  float g0=0,g1=0,g2=0,g3=0;
#pragma unroll
  for (int d = 0; d < 64; d += 4) {
    const float4 hv = *(const float4*)&hb[w][d];
    const float4 wg = *(const float4*)(Wga + lane*128 + d);
    g0 = fmaf(hv.x, wg.x, g0);
    g1 = fmaf(hv.y, wg.y, g1);
    g2 = fmaf(hv.z, wg.z, g2);
    g3 = fmaf(hv.w, wg.w, g3);
  }
#pragma unroll
  for (int d = 0; d < 64; d += 4) {
    const float4 sv = *(const float4*)&sb[w][d];
    const float4 wg = *(const float4*)(Wga + lane*128 + 64 + d);
    g0 = fmaf(sv.x, wg.x, g0);
    g1 = fmaf(sv.y, wg.y, g1);
    g2 = fmaf(sv.z, wg.z, g2);
    g3 = fmaf(sv.w, wg.w, g3);
  }
  const float tg = (g0+g1) + (g2+g3);
  tga[n*64 + lane] = tg;
  atomicAdd(&psum[lane], tg);
  atomicAdd(&pss[lane], tg * tg);
  __syncthreads();
  if (threadIdx.x < 64) atomicAdd(&pstats[threadIdx.x], psum[threadIdx.x]);
  else if (threadIdx.x < 128) atomicAdd(&pstats[threadIdx.x], pss[threadIdx.x - 64]);
}

// ---------------- output: relu(BN5) + transpose to (B,64,N) ----------------
__global__ __launch_bounds__(256,1) void k_out(const float* __restrict__ tga, const float* __restrict__ aff,
                                               float* __restrict__ out) {
  int g = blockIdx.x * 256 + threadIdx.x;
  int nn = g & 4095;
  int e  = (g >> 12) & 63;
  int b  = g >> 18;
  float v = tga[((b << 12) + nn) * 64 + e];
  out[g] = fmaxf(fmaf(v, aff[512 + e], aff[576 + e]), 0.f);
}

extern "C" void kernel_launch(void* const* d_in, const int* in_sizes, int n_in,
                              void* d_out, int out_size, void* d_ws, size_t ws_size,
                              hipStream_t stream) {
  const float* x    = (const float*)d_in[0];
  const float* Wq   = (const float*)d_in[1];
  const float* Wkv  = (const float*)d_in[2];
  const float* Wp1  = (const float*)d_in[3];
  const float* Wp2  = (const float*)d_in[4];
  const float* Wa   = (const float*)d_in[5];
  const float* Wc1  = (const float*)d_in[6];
  const float* Wsk  = (const float*)d_in[7];
  const float* Wga  = (const float*)d_in[8];
  const float* g_p  = (const float*)d_in[9];
  const float* b_p  = (const float*)d_in[10];
  const float* g_a  = (const float*)d_in[11];
  const float* b_a  = (const float*)d_in[12];
  const float* g_c  = (const float*)d_in[13];
  const float* b_c  = (const float*)d_in[14];
  const float* g_sk = (const float*)d_in[15];
  const float* b_sk = (const float*)d_in[16];
  const float* g_ga = (const float*)d_in[17];
  const float* b_ga = (const float*)d_in[18];
  float* W = (float*)d_ws;
  float4*  pts   = (float4*)(W + OFF_PTS);
  int*     idx   = (int*)(W + OFF_IDX);
  float*   tsk   = W + OFF_TSK;
  float*   tc    = W + OFF_TC;
  float*   tga   = W + OFF_TGA;
  float*   prel9 = W + OFF_PREL;
  float*   psk   = W + OFF_PSK;
  float*   pta   = W + OFF_PTA;
  float*   ptc   = W + OFF_PTC;
  float*   ptga  = W + OFF_PTGA;
  float*   aff   = W + OFF_AFF;
  float*   out   = (float*)d_out;

  k_prep<<<64, 256, 0, stream>>>(x, pts, pta, ptc, ptga, prel9, psk);
  k_knn<<<4096, 256, 0, stream>>>(pts, idx, Wsk, tsk, prel9, psk);
  k_fin1<<<1, 64, 0, stream>>>(prel9, psk, Wp1, g_p, b_p, g_sk, b_sk, aff);
  k_entry<0><<<512, 256, 0, stream>>>(pts, idx, Wq, Wkv, Wp1, Wp2, Wa, nullptr, aff, pta, nullptr);
  k_fin2<<<1, 64, 0, stream>>>(pta, (double)NP * (double)KK, g_a, b_a, aff + 128, aff + 192);
  k_entry<1><<<512, 256, 0, stream>>>(pts, idx, Wq, Wkv, Wp1, Wp2, Wa, Wc1, aff, ptc, tc);
  k_fin2<<<1, 64, 0, stream>>>(ptc, (double)NP, g_c, b_c, aff + 256, aff + 320);
  k_final<<<4096, 256, 0, stream>>>(tc, tsk, Wga, aff, tga, ptga);
  k_fin2<<<1, 64, 0, stream>>>(ptga, (double)NP, g_ga, b_ga, aff + 512, aff + 576);
  k_out<<<4096, 256, 0, stream>>>(tga, aff, out);
}